// Round 11
// baseline (174.175 us; speedup 1.0000x reference)
//
#include <hip/hip_runtime.h>
#include <stdint.h>

#define HB 18                   // coarse bucket = top 13 bits of (bits & 0x7fffffff)
#define SH_SIZE 8192
#define NSAMP 65536
#define SMARG 1912              // sample rank margin; DKW P(fail) <= 2e-112
#define DBITS 22                // band width cap in bit patterns
#define CAND_CAP 8192
#define CSORT_CAP 4096          // LDS parallel-sort capacity (expected nC ~100)
#define CBUF_CAP 256
#define LIST_CAP 2500000
#define LBUF_CAP 4096           // 16KB LDS; expected ~1000/block
#define PAIR_CAP 512
#define PEAK_CAP 512
#define MAX_SPIKE 36
#define AB_BLOCKS 128

// params indices
#define P_ULO   0
#define P_UHI   1
#define P_THRLO 2
#define P_THR   3
#define P_CANDN 4
#define P_LISTN 5
#define P_CB    6
#define P_BINA1 7
#define P_BINA2 8
#define P_RA1   9
#define P_RA2   10
#define P_DONES 11
#define P_DONEA 12
#define P_DONEB 13

// ws byte layout (zeroed region first)
#define WS_SHIST  0              // 8192*4 = 32768
#define WS_HISTA  32768          // 2048*4 -> 40960
#define WS_HISTB  40960          // 4096*4 -> 57344
#define WS_PARAMS 57344          // 64 -> 57408
#define WS_ZERO_BYTES 57408
#define WS_CAND   57600          // 8192*4 -> 90368
#define WS_LIST   102400         // 2.5M*4 -> ~10.1MB total

typedef __attribute__((address_space(3))) uint8_t lds8;
typedef __attribute__((address_space(1))) const uint8_t glb8;

__device__ __forceinline__ void async16(const void* g, void* l) {
  // async global->LDS, 16B per lane; LDS dest = wave-uniform base + lane*16
  __builtin_amdgcn_global_load_lds((glb8*)g, (lds8*)l, 16, 0, 0);
}

// ---------------- prep: zero control region + pad output with -1 ----------------
__global__ __launch_bounds__(256) void k_prep(int* __restrict__ ws, int nInts,
                                              float* __restrict__ out, int n2) {
  int j = blockIdx.x * 256 + threadIdx.x;
  if (j < nInts) ws[j] = 0;
  if (j < n2) out[j] = -1.0f;
}

// ---------------- sample 65536 strided elements -> coarse hist; last block picks band ----------------
__global__ __launch_bounds__(256) void k_sample(const float* __restrict__ x, int N,
                                                int* __restrict__ shist,
                                                int* __restrict__ p) {
  __shared__ int h[SH_SIZE];
  __shared__ int lastS;
  __shared__ int part[256];
  __shared__ int excl[256];
  __shared__ uint32_t uLoS, uHiS;
  int tid = threadIdx.x;
  for (int i = tid; i < SH_SIZE; i += 256) h[i] = 0;
  __syncthreads();
  int stride = N / NSAMP; if (stride < 1) stride = 1;
  for (int i = blockIdx.x * 256 + tid; i < NSAMP; i += gridDim.x * 256) {
    long long idx = (long long)i * stride;
    if (idx < N) {
      uint32_t u = __float_as_uint(x[idx]) & 0x7fffffffu;
      atomicAdd(&h[u >> HB], 1);
    }
  }
  __syncthreads();
  for (int i = tid; i < SH_SIZE; i += 256) {
    int c = h[i];
    if (c) atomicAdd(&shist[i], c);
  }
  __threadfence();
  if (tid == 0) lastS = (atomicAdd(&p[P_DONES], 1) == (int)gridDim.x - 1);
  __syncthreads();
  if (!lastS) return;
  __threadfence();
  // ---- bandsel (last block only) ----
  const int chunk = SH_SIZE / 256;  // 32
  int base = tid * chunk;
  int s = 0;
  int cc[chunk];
  for (int w = 0; w < chunk; ++w) { cc[w] = shist[base + w]; s += cc[w]; }
  part[tid] = s;
  __syncthreads();
  if (tid == 0) { int a = 0; for (int i = 0; i < 256; ++i) { excl[i] = a; a += part[i]; } }
  __syncthreads();
  int pre = excl[tid];
  int sA = NSAMP / 2 - SMARG, sB = NSAMP / 2 + SMARG;
  if (pre <= sA && sA < pre + s) {
    int a = pre;
    for (int w = 0; w < chunk; ++w) {
      if (sA < a + cc[w]) { uLoS = (uint32_t)(base + w) << HB; break; }
      a += cc[w];
    }
  }
  if (pre <= sB && sB < pre + s) {
    int a = pre;
    for (int w = 0; w < chunk; ++w) {
      if (sB < a + cc[w]) { uHiS = (uint32_t)(base + w + 1) << HB; break; }
      a += cc[w];
    }
  }
  __syncthreads();
  if (tid == 0) {
    uint32_t uLo = uLoS, uHi = uHiS;
    if (uHi - uLo > (1u << DBITS)) uHi = uLo + (1u << DBITS);
    p[P_ULO] = (int)uLo;
    p[P_UHI] = (int)uHi;
    float vLo = __uint_as_float(uLo);   // vLo <= both median order stats
    p[P_THRLO] = __float_as_int((5.0f * vLo / 0.6745f) * 0.999f);
  }
}

// ---------------- single full pass: async LDS staging, LDS-only hot loop ----------------
__device__ __forceinline__ void m_elem(uint32_t fbits, int idx, uint32_t uLo, uint32_t bw,
                                       uint32_t thrBits, int* lbuf, int* lcnt,
                                       int* cbuf, int* ccnt, int& cb) {
  uint32_t u = fbits & 0x7fffffffu;
  cb += (u < uLo) ? 1 : 0;
  if (u - uLo < bw) {                 // unsigned wrap => single compare band test
    int id = atomicAdd(lcnt, 1);
    if (id < LBUF_CAP) lbuf[id] = (int)(u - uLo);
  }
  if (u > thrBits) {                  // positive-float order == bit order
    int id = atomicAdd(ccnt, 1);
    if (id < CBUF_CAP) cbuf[id] = idx;
  }
}

__global__ __launch_bounds__(256) void k_main(const float* __restrict__ x, int N,
                                              int* __restrict__ p,
                                              int* __restrict__ list,
                                              int* __restrict__ cand) {
  __shared__ __align__(16) uint8_t stage[2][16384];   // double-buffered 16KB tiles
  __shared__ int lbuf[LBUF_CAP];
  __shared__ int cbuf[CBUF_CAP];
  __shared__ int red[256];
  __shared__ int lcnt, ccnt, lbase, cbase;
  int tid = threadIdx.x;
  if (tid == 0) { lcnt = 0; ccnt = 0; }
  __syncthreads();
  uint32_t uLo = (uint32_t)p[P_ULO];
  uint32_t bw  = (uint32_t)p[P_UHI] - uLo;
  uint32_t thrBits = (uint32_t)p[P_THRLO];
  int cb = 0;
  int NV = N >> 2;
  int nTiles = NV >> 10;              // 1024 uint4 (16KB) per tile
  const uint4* vec = reinterpret_cast<const uint4*>(x);
  int G = gridDim.x;
  int t = blockIdx.x;
  if (t < nTiles) {                   // prologue: issue first tile into buf0
    const uint8_t* g = (const uint8_t*)(vec + ((long long)t << 10));
#pragma unroll
    for (int r = 0; r < 4; ++r)
      async16(g + (((r << 8) + tid) << 4), &stage[0][((r << 8) + tid) << 4]);
  }
  int i = 0;
  for (; t < nTiles; t += G, ++i) {
    int cur = i & 1;
    int tn = t + G;
    if (tn < nTiles) {                // prefetch next tile into other buffer
      const uint8_t* g = (const uint8_t*)(vec + ((long long)tn << 10));
#pragma unroll
      for (int r = 0; r < 4; ++r)
        async16(g + (((r << 8) + tid) << 4), &stage[cur ^ 1][((r << 8) + tid) << 4]);
    }
    asm volatile("s_waitcnt vmcnt(0)" ::: "memory");   // tile t landed in LDS
    __syncthreads();
    const uint4* sb = reinterpret_cast<const uint4*>(&stage[cur][0]);
    int eb = t << 12;                 // element base = t*4096
#pragma unroll
    for (int r = 0; r < 4; ++r) {
      uint4 v = sb[(r << 8) + tid];
      int ei = eb + (((r << 8) + tid) << 2);
      m_elem(v.x, ei + 0, uLo, bw, thrBits, lbuf, &lcnt, cbuf, &ccnt, cb);
      m_elem(v.y, ei + 1, uLo, bw, thrBits, lbuf, &lcnt, cbuf, &ccnt, cb);
      m_elem(v.z, ei + 2, uLo, bw, thrBits, lbuf, &lcnt, cbuf, &ccnt, cb);
      m_elem(v.w, ei + 3, uLo, bw, thrBits, lbuf, &lcnt, cbuf, &ccnt, cb);
    }
    __syncthreads();                  // buf[cur] free for reuse next iteration
  }
  // remainder uint4s [nTiles*1024, NV) — direct loads, tiny
  for (int j = (nTiles << 10) + blockIdx.x * 256 + tid; j < NV; j += G * 256) {
    uint4 a = vec[j];
    int ei = j << 2;
    m_elem(a.x, ei + 0, uLo, bw, thrBits, lbuf, &lcnt, cbuf, &ccnt, cb);
    m_elem(a.y, ei + 1, uLo, bw, thrBits, lbuf, &lcnt, cbuf, &ccnt, cb);
    m_elem(a.z, ei + 2, uLo, bw, thrBits, lbuf, &lcnt, cbuf, &ccnt, cb);
    m_elem(a.w, ei + 3, uLo, bw, thrBits, lbuf, &lcnt, cbuf, &ccnt, cb);
  }
  if (blockIdx.x == 0 && tid == 0) {              // tail (N % 4); empty when N%4==0
    for (int i2 = NV << 2; i2 < N; ++i2)
      m_elem(__float_as_uint(x[i2]), i2, uLo, bw, thrBits, lbuf, &lcnt, cbuf, &ccnt, cb);
  }
  __syncthreads();
  int nl = lcnt < LBUF_CAP ? lcnt : LBUF_CAP;
  int nc = ccnt < CBUF_CAP ? ccnt : CBUF_CAP;
  if (tid == 0) {                                  // one global atomic each, per block
    lbase = atomicAdd(&p[P_LISTN], nl);
    cbase = atomicAdd(&p[P_CANDN], nc);
  }
  red[tid] = cb;
  __syncthreads();
  for (int s2 = 128; s2; s2 >>= 1) {
    if (tid < s2) red[tid] += red[tid + s2];
    __syncthreads();
  }
  if (tid == 0) atomicAdd(&p[P_CB], red[0]);
  for (int i2 = tid; i2 < nl; i2 += 256)
    if (lbase + i2 < LIST_CAP) list[lbase + i2] = lbuf[i2];
  for (int i2 = tid; i2 < nc; i2 += 256)
    if (cbase + i2 < CAND_CAP) cand[cbase + i2] = cbuf[i2];
}

// ---------------- stage A: 2048-bin hist of d>>11; last block selects both ranks ----------------
__global__ __launch_bounds__(256) void k_stageA(const int* __restrict__ list,
                                                int* __restrict__ p,
                                                int* __restrict__ histA, int N) {
  __shared__ int h[2048];
  __shared__ int lastS;
  __shared__ int part[256];
  __shared__ int excl[256];
  int tid = threadIdx.x;
  for (int i = tid; i < 2048; i += 256) h[i] = 0;
  __syncthreads();
  int n = p[P_LISTN]; if (n > LIST_CAP) n = LIST_CAP;
  int str = gridDim.x * 256;
  for (int i = blockIdx.x * 256 + tid; i < n; i += str)
    atomicAdd(&h[list[i] >> 11], 1);
  __syncthreads();
  for (int i = tid; i < 2048; i += 256) {
    int c = h[i];
    if (c) atomicAdd(&histA[i], c);
  }
  __threadfence();
  if (tid == 0) lastS = (atomicAdd(&p[P_DONEA], 1) == (int)gridDim.x - 1);
  __syncthreads();
  if (!lastS) return;
  __threadfence();
  long long k1 = (long long)(N / 2) - 1, k2 = (long long)(N / 2);
  long long cb = p[P_CB];
  long long r1l = k1 - cb, r2l = k2 - cb;
  if (r1l < 0) r1l = 0; if (r1l > n - 1) r1l = n - 1;   // sanity clamp
  if (r2l < 0) r2l = 0; if (r2l > n - 1) r2l = n - 1;
  int r1 = (int)r1l, r2 = (int)r2l;
  int base = tid * 8;
  int cc[8]; int s = 0;
#pragma unroll
  for (int w = 0; w < 8; ++w) { cc[w] = histA[base + w]; s += cc[w]; }
  part[tid] = s;
  __syncthreads();
  if (tid == 0) { int a = 0; for (int i = 0; i < 256; ++i) { excl[i] = a; a += part[i]; } }
  __syncthreads();
  int pre = excl[tid];
  if (pre <= r1 && r1 < pre + s) {
    int a = pre;
    for (int w = 0; w < 8; ++w) {
      if (r1 < a + cc[w]) { p[P_BINA1] = base + w; p[P_RA1] = r1 - a; break; }
      a += cc[w];
    }
  }
  if (pre <= r2 && r2 < pre + s) {
    int a = pre;
    for (int w = 0; w < 8; ++w) {
      if (r2 < a + cc[w]) { p[P_BINA2] = base + w; p[P_RA2] = r2 - a; break; }
      a += cc[w];
    }
  }
}

// ---------------- finalize helpers ----------------
__device__ static void isort(int* a, int n) {
  for (int i = 1; i < n; ++i) {
    int v = a[i]; int j = i - 1;
    while (j >= 0 && a[j] > v) { a[j + 1] = a[j]; --j; }
    a[j + 1] = v;
  }
}

__device__ inline void eval_pair(const float* __restrict__ x, int p, float thr,
                                 int* pe, int* px, int* ne, int* nx, int* cnt) {
  float a = x[p], b = x[p + 1];
  bool m0 = a > thr, m1 = b > thr;
  if (m0 != m1) {
    int id = atomicAdd(&cnt[m1 ? 0 : 1], 1);
    if (id < PAIR_CAP) (m1 ? pe : px)[id] = p;
  }
  bool q0 = (-a) > thr, q1 = (-b) > thr;       // exact ref form: v=-x, v>thr
  if (q0 != q1) {
    int id = atomicAdd(&cnt[q1 ? 2 : 3], 1);
    if (id < PAIR_CAP) (q1 ? ne : nx)[id] = p;
  }
}

__device__ inline int wave_argmax36(const float* __restrict__ x, int N, int sign,
                                    int e, int lane) {
  float val = -INFINITY;
  int wi = lane;
  if (lane < MAX_SPIKE) {
    int idx = e + lane; if (idx > N - 1) idx = N - 1;   // ref: clip(entry+w, 0, N-1)
    float v = x[idx];
    val = (sign < 0) ? -v : v;
  }
  for (int off = 32; off; off >>= 1) {                  // tie -> smaller w (first max)
    float ov = __shfl_xor(val, off);
    int owi = __shfl_xor(wi, off);
    if (ov > val || (ov == val && owi < wi)) { val = ov; wi = owi; }
  }
  return e + wi;
}

__device__ inline int proc_pol(const float* __restrict__ x, int N, int sign,
                               const int* eL, int nE, const int* xL, int nX,
                               int* pk, int lane) {
  int n = nE < nX ? nE : nX;
  int tot = 0;
  for (int t = 0; t < n; ++t) {
    int dur = xL[t] - eL[t];
    if (dur <= MAX_SPIKE) {                    // negative dur kept (ref semantics)
      int pp = wave_argmax36(x, N, sign, eL[t], lane);
      if (tot < PEAK_CAP && lane == 0) pk[tot] = pp;
      ++tot;
    }
  }
  if (tot > PEAK_CAP) tot = PEAK_CAP;
  if (lane == 0) isort(pk, tot);               // LDS array; ref sorts peaks
  return tot;
}

// ---------------- stage B: low-11-bit hists; last block -> threshold + finalize ----------------
__global__ __launch_bounds__(256) void k_stageB(const float* __restrict__ x, int N,
                                                const int* __restrict__ list,
                                                int* __restrict__ p,
                                                int* __restrict__ histB,
                                                int* __restrict__ cand,
                                                float* __restrict__ out, int OUT_K) {
  __shared__ int h[4096];
  __shared__ int lastS;
  __shared__ int part[256];
  __shared__ int excl[256];
  __shared__ float vres[2];
  __shared__ float sthr;
  __shared__ int cl[CSORT_CAP];               // LDS candidate sort array (16KB)
  __shared__ int pe[PAIR_CAP], px[PAIR_CAP], ne[PAIR_CAP], nx[PAIR_CAP];
  __shared__ int cnt[4];
  __shared__ int pkP[PEAK_CAP], pkN[PEAK_CAP];
  __shared__ int nPk[2];
  int tid = threadIdx.x;
  for (int i = tid; i < 4096; i += 256) h[i] = 0;
  __syncthreads();
  int n = p[P_LISTN]; if (n > LIST_CAP) n = LIST_CAP;
  int binA1 = p[P_BINA1], binA2 = p[P_BINA2];
  int str = gridDim.x * 256;
  for (int i = blockIdx.x * 256 + tid; i < n; i += str) {
    int d = list[i];
    int hi = d >> 11, lo = d & 2047;
    if (hi == binA1) atomicAdd(&h[lo], 1);
    if (hi == binA2) atomicAdd(&h[2048 + lo], 1);
  }
  __syncthreads();
  for (int i = tid; i < 4096; i += 256) {
    int c = h[i];
    if (c) atomicAdd(&histB[i], c);
  }
  __threadfence();
  if (tid == 0) lastS = (atomicAdd(&p[P_DONEB], 1) == (int)gridDim.x - 1);
  __syncthreads();
  if (!lastS) return;
  __threadfence();
  // ---- exact threshold (last block) ----
  uint32_t uLo = (uint32_t)p[P_ULO];
  if (tid < 2) vres[tid] = __uint_as_float(uLo);
  for (int tgt = 0; tgt < 2; ++tgt) {
    __syncthreads();
    const int* hh = histB + tgt * 2048;
    int rank = (tgt == 0) ? p[P_RA1] : p[P_RA2];
    int binA = (tgt == 0) ? binA1 : binA2;
    int base = tid * 8;
    int cc[8]; int s = 0;
#pragma unroll
    for (int w = 0; w < 8; ++w) { cc[w] = hh[base + w]; s += cc[w]; }
    part[tid] = s;
    __syncthreads();
    if (tid == 0) { int a = 0; for (int i = 0; i < 256; ++i) { excl[i] = a; a += part[i]; } }
    __syncthreads();
    int pre = excl[tid];
    if (pre <= rank && rank < pre + s) {
      int a = pre;
      for (int w = 0; w < 8; ++w) {
        if (rank < a + cc[w]) {
          uint32_t bits = uLo + ((uint32_t)binA << 11) + (uint32_t)(base + w);
          vres[tgt] = __uint_as_float(bits);
          break;
        }
        a += cc[w];
      }
    }
  }
  __syncthreads();
  if (tid == 0) {
    float med = 0.5f * (vres[0] + vres[1]);     // np.median: mean of two mid order stats
    float thr = (5.0f * med) / 0.6745f;         // reference float32 expression order
    p[P_THR] = __float_as_int(thr);
    sthr = thr;
    out[2 * OUT_K] = thr;
  }
  if (tid < 4) cnt[tid] = 0;
  __syncthreads();
  // ---- finalize (same block) ----
  float thr = sthr;
  int nC = p[P_CANDN]; if (nC > CAND_CAP) nC = CAND_CAP;
  const int* cnd;                              // sorted candidate array to use
  if (nC <= CSORT_CAP) {
    // parallel rank sort entirely in LDS (indices are distinct)
    for (int i = tid; i < nC; i += 256) cl[i] = cand[i];
    __syncthreads();
    int myv[CSORT_CAP / 256], myr[CSORT_CAP / 256], nh = 0;
    for (int i = tid; i < nC; i += 256) {
      int v = cl[i];
      int r = 0;
      for (int q = 0; q < nC; ++q) r += (cl[q] < v) ? 1 : 0;
      myv[nh] = v; myr[nh] = r; ++nh;
    }
    __syncthreads();
    for (int t = 0; t < nh; ++t) cl[myr[t]] = myv[t];
    __syncthreads();
    cnd = cl;
  } else {                                      // escape hatch, never expected
    if (tid == 0) isort(cand, nC);
    __syncthreads();
    cnd = cand;
  }
  // pair (p,p+1) processed exactly once: from candidate p (right pair),
  // or from candidate p+1 iff p not a candidate.
  for (int k = tid; k < nC; k += 256) {
    int c = cnd[k];
    bool prevAdj = (k > 0) && (cnd[k - 1] == c - 1);
    if (c > 0 && !prevAdj) eval_pair(x, c - 1, thr, pe, px, ne, nx, cnt);
    if (c <= N - 2) eval_pair(x, c, thr, pe, px, ne, nx, cnt);
  }
  __syncthreads();
  int nPE = min(cnt[0], PAIR_CAP), nPX = min(cnt[1], PAIR_CAP);
  int nNE = min(cnt[2], PAIR_CAP), nNX = min(cnt[3], PAIR_CAP);
  if (tid == 0) { isort(pe, nPE); isort(px, nPX); }
  else if (tid == 1) { isort(ne, nNE); isort(nx, nNX); }
  __syncthreads();
  if (tid < 64) {                               // wave 0 only; no barriers inside
    int t0 = proc_pol(x, N, +1, pe, nPE, px, nPX, pkP, tid);
    int t1 = proc_pol(x, N, -1, ne, nNE, nx, nNX, pkN, tid);
    if (tid == 0) { nPk[0] = t0; nPk[1] = t1; }
  }
  __syncthreads();
  for (int j = tid; j < nPk[0]; j += 256) out[j] = (float)pkP[j];
  for (int j = tid; j < nPk[1]; j += 256) out[OUT_K + j] = (float)pkN[j];
}

extern "C" void kernel_launch(void* const* d_in, const int* in_sizes, int n_in,
                              void* d_out, int out_size, void* d_ws, size_t ws_size,
                              hipStream_t stream) {
  const float* x = (const float*)d_in[0];
  int N = in_sizes[0];
  float* out = (float*)d_out;
  char* ws = (char*)d_ws;

  int* shist  = (int*)(ws + WS_SHIST);
  int* histA  = (int*)(ws + WS_HISTA);
  int* histB  = (int*)(ws + WS_HISTB);
  int* params = (int*)(ws + WS_PARAMS);
  int* cand   = (int*)(ws + WS_CAND);
  int* list   = (int*)(ws + WS_LIST);

  int OUT_K = (out_size - 1) / 2;  // 65536
  int nInts = WS_ZERO_BYTES / 4;
  int prepN = 2 * OUT_K;           // covers both zero region and pad region

  k_prep<<<(prepN + 255) / 256, 256, 0, stream>>>((int*)ws, nInts, out, prepN);
  k_sample<<<64, 256, 0, stream>>>(x, N, shist, params);
  k_main<<<2048, 256, 0, stream>>>(x, N, params, list, cand);
  k_stageA<<<AB_BLOCKS, 256, 0, stream>>>(list, params, histA, N);
  k_stageB<<<AB_BLOCKS, 256, 0, stream>>>(x, N, list, params, histB, cand, out, OUT_K);
}

// Round 12
// 141.120 us; speedup vs baseline: 1.2342x; 1.2342x over previous
//
#include <hip/hip_runtime.h>
#include <stdint.h>

#define HB 18                   // coarse bucket = top 13 bits of (bits & 0x7fffffff)
#define SH_SIZE 8192
#define NSAMP 65536
#define SMARG 1912              // sample rank margin; DKW P(fail) <= 2e-112
#define DBITS 22                // band width cap in bit patterns
#define CAND_CAP 8192
#define CSORT_CAP 4096          // LDS parallel-sort capacity (expected nC ~100)
#define CBUF_CAP 256
#define LIST_CAP 2500000
#define LBUF_CAP 4096           // 16KB LDS; expected ~2400/block at G=1024
#define PAIR_CAP 512
#define PEAK_CAP 512
#define MAX_SPIKE 36
#define AB_BLOCKS 128
#define MAIN_BLOCKS 1024        // exactly 4 blocks/CU -> all resident, no dispatch rounds

// params indices
#define P_ULO   0
#define P_UHI   1
#define P_THRLO 2
#define P_THR   3
#define P_CANDN 4
#define P_LISTN 5
#define P_CB    6
#define P_BINA1 7
#define P_BINA2 8
#define P_RA1   9
#define P_RA2   10
#define P_DONES 11
#define P_DONEA 12
#define P_DONEB 13

// ws byte layout (zeroed region first)
#define WS_SHIST  0              // 8192*4 = 32768
#define WS_HISTA  32768          // 2048*4 -> 40960
#define WS_HISTB  40960          // 4096*4 -> 57344
#define WS_PARAMS 57344          // 64 -> 57408
#define WS_ZERO_BYTES 57408
#define WS_CAND   57600          // 8192*4 -> 90368
#define WS_LIST   102400         // 2.5M*4 -> ~10.1MB total

// ---------------- prep: zero control region + pad output with -1 ----------------
__global__ __launch_bounds__(256) void k_prep(int* __restrict__ ws, int nInts,
                                              float* __restrict__ out, int n2) {
  int j = blockIdx.x * 256 + threadIdx.x;
  if (j < nInts) ws[j] = 0;
  if (j < n2) out[j] = -1.0f;
}

// ---------------- sample 65536 strided elements -> coarse hist; last block picks band ----------------
__global__ __launch_bounds__(256) void k_sample(const float* __restrict__ x, int N,
                                                int* __restrict__ shist,
                                                int* __restrict__ p) {
  __shared__ int h[SH_SIZE];
  __shared__ int lastS;
  __shared__ int part[256];
  __shared__ int excl[256];
  __shared__ uint32_t uLoS, uHiS;
  int tid = threadIdx.x;
  for (int i = tid; i < SH_SIZE; i += 256) h[i] = 0;
  __syncthreads();
  int stride = N / NSAMP; if (stride < 1) stride = 1;
  for (int i = blockIdx.x * 256 + tid; i < NSAMP; i += gridDim.x * 256) {
    long long idx = (long long)i * stride;
    if (idx < N) {
      uint32_t u = __float_as_uint(x[idx]) & 0x7fffffffu;
      atomicAdd(&h[u >> HB], 1);
    }
  }
  __syncthreads();
  for (int i = tid; i < SH_SIZE; i += 256) {
    int c = h[i];
    if (c) atomicAdd(&shist[i], c);
  }
  __threadfence();
  if (tid == 0) lastS = (atomicAdd(&p[P_DONES], 1) == (int)gridDim.x - 1);
  __syncthreads();
  if (!lastS) return;
  __threadfence();
  // ---- bandsel (last block only) ----
  const int chunk = SH_SIZE / 256;  // 32
  int base = tid * chunk;
  int s = 0;
  int cc[chunk];
  for (int w = 0; w < chunk; ++w) { cc[w] = shist[base + w]; s += cc[w]; }
  part[tid] = s;
  __syncthreads();
  if (tid == 0) { int a = 0; for (int i = 0; i < 256; ++i) { excl[i] = a; a += part[i]; } }
  __syncthreads();
  int pre = excl[tid];
  int sA = NSAMP / 2 - SMARG, sB = NSAMP / 2 + SMARG;
  if (pre <= sA && sA < pre + s) {
    int a = pre;
    for (int w = 0; w < chunk; ++w) {
      if (sA < a + cc[w]) { uLoS = (uint32_t)(base + w) << HB; break; }
      a += cc[w];
    }
  }
  if (pre <= sB && sB < pre + s) {
    int a = pre;
    for (int w = 0; w < chunk; ++w) {
      if (sB < a + cc[w]) { uHiS = (uint32_t)(base + w + 1) << HB; break; }
      a += cc[w];
    }
  }
  __syncthreads();
  if (tid == 0) {
    uint32_t uLo = uLoS, uHi = uHiS;
    if (uHi - uLo > (1u << DBITS)) uHi = uLo + (1u << DBITS);
    p[P_ULO] = (int)uLo;
    p[P_UHI] = (int)uHi;
    float vLo = __uint_as_float(uLo);   // vLo <= both median order stats
    p[P_THRLO] = __float_as_int((5.0f * vLo / 0.6745f) * 0.999f);
  }
}

// ---------------- single full pass: register-burst streaming, LDS-only pushes ----------------
__device__ __forceinline__ void m_elem(uint32_t fbits, int idx, uint32_t uLo, uint32_t bw,
                                       uint32_t thrBits, int* lbuf, int* lcnt,
                                       int* cbuf, int* ccnt, int& cb) {
  uint32_t u = fbits & 0x7fffffffu;
  cb += (u < uLo) ? 1 : 0;
  if (u - uLo < bw) {                 // unsigned wrap => single compare band test
    int id = atomicAdd(lcnt, 1);
    if (id < LBUF_CAP) lbuf[id] = (int)(u - uLo);
  }
  if (u > thrBits) {                  // positive-float order == bit order
    int id = atomicAdd(ccnt, 1);
    if (id < CBUF_CAP) cbuf[id] = idx;
  }
}

__global__ __launch_bounds__(256) void k_main(const float* __restrict__ x, int N,
                                              int* __restrict__ p,
                                              int* __restrict__ list,
                                              int* __restrict__ cand) {
  __shared__ int lbuf[LBUF_CAP];
  __shared__ int cbuf[CBUF_CAP];
  __shared__ int red[256];
  __shared__ int lcnt, ccnt, lbase, cbase;
  int tid = threadIdx.x;
  if (tid == 0) { lcnt = 0; ccnt = 0; }
  __syncthreads();
  uint32_t uLo = (uint32_t)p[P_ULO];
  uint32_t bw  = (uint32_t)p[P_UHI] - uLo;
  uint32_t thrBits = (uint32_t)p[P_THRLO];
  int cb = 0;
  int NV = N >> 2;
  int nTiles = NV >> 11;              // tile = 2048 uint4 (32KB), 8 uint4/thread
  const uint4* vec = reinterpret_cast<const uint4*>(x);
  for (int t = blockIdx.x; t < nTiles; t += gridDim.x) {
    const uint4* bp = vec + ((long long)t << 11) + tid;
    // 8 coalesced dwordx4 loads; the memory-clobber fence below blocks IR-level
    // load sinking, forcing all 8 in flight per wave (true 8-deep burst).
    uint4 v0 = bp[0];
    uint4 v1 = bp[256];
    uint4 v2 = bp[512];
    uint4 v3 = bp[768];
    uint4 v4 = bp[1024];
    uint4 v5 = bp[1280];
    uint4 v6 = bp[1536];
    uint4 v7 = bp[1792];
    asm volatile("" ::: "memory");    // IR + MIR fence: loads stay above, uses below
    int eb = (t << 13) + (tid << 2);  // element base
#define PROC(vk, koff)                                                              \
    m_elem(vk.x, eb + (koff) + 0, uLo, bw, thrBits, lbuf, &lcnt, cbuf, &ccnt, cb);  \
    m_elem(vk.y, eb + (koff) + 1, uLo, bw, thrBits, lbuf, &lcnt, cbuf, &ccnt, cb);  \
    m_elem(vk.z, eb + (koff) + 2, uLo, bw, thrBits, lbuf, &lcnt, cbuf, &ccnt, cb);  \
    m_elem(vk.w, eb + (koff) + 3, uLo, bw, thrBits, lbuf, &lcnt, cbuf, &ccnt, cb)
    PROC(v0, 0);
    PROC(v1, 1024);
    PROC(v2, 2048);
    PROC(v3, 3072);
    PROC(v4, 4096);
    PROC(v5, 5120);
    PROC(v6, 6144);
    PROC(v7, 7168);
#undef PROC
  }
  // remainder uint4s [nTiles*2048, NV)
  for (int j = (nTiles << 11) + blockIdx.x * 256 + tid; j < NV; j += gridDim.x * 256) {
    uint4 a = vec[j];
    int ei = j << 2;
    m_elem(a.x, ei + 0, uLo, bw, thrBits, lbuf, &lcnt, cbuf, &ccnt, cb);
    m_elem(a.y, ei + 1, uLo, bw, thrBits, lbuf, &lcnt, cbuf, &ccnt, cb);
    m_elem(a.z, ei + 2, uLo, bw, thrBits, lbuf, &lcnt, cbuf, &ccnt, cb);
    m_elem(a.w, ei + 3, uLo, bw, thrBits, lbuf, &lcnt, cbuf, &ccnt, cb);
  }
  if (blockIdx.x == 0 && tid == 0) {              // tail (N % 4); empty when N%4==0
    for (int i2 = NV << 2; i2 < N; ++i2)
      m_elem(__float_as_uint(x[i2]), i2, uLo, bw, thrBits, lbuf, &lcnt, cbuf, &ccnt, cb);
  }
  __syncthreads();
  int nl = lcnt < LBUF_CAP ? lcnt : LBUF_CAP;
  int nc = ccnt < CBUF_CAP ? ccnt : CBUF_CAP;
  if (tid == 0) {                                  // one global atomic each, per block
    lbase = atomicAdd(&p[P_LISTN], nl);
    cbase = atomicAdd(&p[P_CANDN], nc);
  }
  red[tid] = cb;
  __syncthreads();
  for (int s2 = 128; s2; s2 >>= 1) {
    if (tid < s2) red[tid] += red[tid + s2];
    __syncthreads();
  }
  if (tid == 0) atomicAdd(&p[P_CB], red[0]);
  for (int i2 = tid; i2 < nl; i2 += 256)
    if (lbase + i2 < LIST_CAP) list[lbase + i2] = lbuf[i2];
  for (int i2 = tid; i2 < nc; i2 += 256)
    if (cbase + i2 < CAND_CAP) cand[cbase + i2] = cbuf[i2];
}

// ---------------- stage A: 2048-bin hist of d>>11; last block selects both ranks ----------------
__global__ __launch_bounds__(256) void k_stageA(const int* __restrict__ list,
                                                int* __restrict__ p,
                                                int* __restrict__ histA, int N) {
  __shared__ int h[2048];
  __shared__ int lastS;
  __shared__ int part[256];
  __shared__ int excl[256];
  int tid = threadIdx.x;
  for (int i = tid; i < 2048; i += 256) h[i] = 0;
  __syncthreads();
  int n = p[P_LISTN]; if (n > LIST_CAP) n = LIST_CAP;
  int str = gridDim.x * 256;
  for (int i = blockIdx.x * 256 + tid; i < n; i += str)
    atomicAdd(&h[list[i] >> 11], 1);
  __syncthreads();
  for (int i = tid; i < 2048; i += 256) {
    int c = h[i];
    if (c) atomicAdd(&histA[i], c);
  }
  __threadfence();
  if (tid == 0) lastS = (atomicAdd(&p[P_DONEA], 1) == (int)gridDim.x - 1);
  __syncthreads();
  if (!lastS) return;
  __threadfence();
  long long k1 = (long long)(N / 2) - 1, k2 = (long long)(N / 2);
  long long cb = p[P_CB];
  long long r1l = k1 - cb, r2l = k2 - cb;
  if (r1l < 0) r1l = 0; if (r1l > n - 1) r1l = n - 1;   // sanity clamp
  if (r2l < 0) r2l = 0; if (r2l > n - 1) r2l = n - 1;
  int r1 = (int)r1l, r2 = (int)r2l;
  int base = tid * 8;
  int cc[8]; int s = 0;
#pragma unroll
  for (int w = 0; w < 8; ++w) { cc[w] = histA[base + w]; s += cc[w]; }
  part[tid] = s;
  __syncthreads();
  if (tid == 0) { int a = 0; for (int i = 0; i < 256; ++i) { excl[i] = a; a += part[i]; } }
  __syncthreads();
  int pre = excl[tid];
  if (pre <= r1 && r1 < pre + s) {
    int a = pre;
    for (int w = 0; w < 8; ++w) {
      if (r1 < a + cc[w]) { p[P_BINA1] = base + w; p[P_RA1] = r1 - a; break; }
      a += cc[w];
    }
  }
  if (pre <= r2 && r2 < pre + s) {
    int a = pre;
    for (int w = 0; w < 8; ++w) {
      if (r2 < a + cc[w]) { p[P_BINA2] = base + w; p[P_RA2] = r2 - a; break; }
      a += cc[w];
    }
  }
}

// ---------------- finalize helpers ----------------
__device__ static void isort(int* a, int n) {
  for (int i = 1; i < n; ++i) {
    int v = a[i]; int j = i - 1;
    while (j >= 0 && a[j] > v) { a[j + 1] = a[j]; --j; }
    a[j + 1] = v;
  }
}

__device__ inline void eval_pair(const float* __restrict__ x, int p, float thr,
                                 int* pe, int* px, int* ne, int* nx, int* cnt) {
  float a = x[p], b = x[p + 1];
  bool m0 = a > thr, m1 = b > thr;
  if (m0 != m1) {
    int id = atomicAdd(&cnt[m1 ? 0 : 1], 1);
    if (id < PAIR_CAP) (m1 ? pe : px)[id] = p;
  }
  bool q0 = (-a) > thr, q1 = (-b) > thr;       // exact ref form: v=-x, v>thr
  if (q0 != q1) {
    int id = atomicAdd(&cnt[q1 ? 2 : 3], 1);
    if (id < PAIR_CAP) (q1 ? ne : nx)[id] = p;
  }
}

__device__ inline int wave_argmax36(const float* __restrict__ x, int N, int sign,
                                    int e, int lane) {
  float val = -INFINITY;
  int wi = lane;
  if (lane < MAX_SPIKE) {
    int idx = e + lane; if (idx > N - 1) idx = N - 1;   // ref: clip(entry+w, 0, N-1)
    float v = x[idx];
    val = (sign < 0) ? -v : v;
  }
  for (int off = 32; off; off >>= 1) {                  // tie -> smaller w (first max)
    float ov = __shfl_xor(val, off);
    int owi = __shfl_xor(wi, off);
    if (ov > val || (ov == val && owi < wi)) { val = ov; wi = owi; }
  }
  return e + wi;
}

__device__ inline int proc_pol(const float* __restrict__ x, int N, int sign,
                               const int* eL, int nE, const int* xL, int nX,
                               int* pk, int lane) {
  int n = nE < nX ? nE : nX;
  int tot = 0;
  for (int t = 0; t < n; ++t) {
    int dur = xL[t] - eL[t];
    if (dur <= MAX_SPIKE) {                    // negative dur kept (ref semantics)
      int pp = wave_argmax36(x, N, sign, eL[t], lane);
      if (tot < PEAK_CAP && lane == 0) pk[tot] = pp;
      ++tot;
    }
  }
  if (tot > PEAK_CAP) tot = PEAK_CAP;
  if (lane == 0) isort(pk, tot);               // LDS array; ref sorts peaks
  return tot;
}

// ---------------- stage B: low-11-bit hists; last block -> threshold + finalize ----------------
__global__ __launch_bounds__(256) void k_stageB(const float* __restrict__ x, int N,
                                                const int* __restrict__ list,
                                                int* __restrict__ p,
                                                int* __restrict__ histB,
                                                int* __restrict__ cand,
                                                float* __restrict__ out, int OUT_K) {
  __shared__ int h[4096];
  __shared__ int lastS;
  __shared__ int part[256];
  __shared__ int excl[256];
  __shared__ float vres[2];
  __shared__ float sthr;
  __shared__ int cl[CSORT_CAP];               // LDS candidate sort array (16KB)
  __shared__ int pe[PAIR_CAP], px[PAIR_CAP], ne[PAIR_CAP], nx[PAIR_CAP];
  __shared__ int cnt[4];
  __shared__ int pkP[PEAK_CAP], pkN[PEAK_CAP];
  __shared__ int nPk[2];
  int tid = threadIdx.x;
  for (int i = tid; i < 4096; i += 256) h[i] = 0;
  __syncthreads();
  int n = p[P_LISTN]; if (n > LIST_CAP) n = LIST_CAP;
  int binA1 = p[P_BINA1], binA2 = p[P_BINA2];
  int str = gridDim.x * 256;
  for (int i = blockIdx.x * 256 + tid; i < n; i += str) {
    int d = list[i];
    int hi = d >> 11, lo = d & 2047;
    if (hi == binA1) atomicAdd(&h[lo], 1);
    if (hi == binA2) atomicAdd(&h[2048 + lo], 1);
  }
  __syncthreads();
  for (int i = tid; i < 4096; i += 256) {
    int c = h[i];
    if (c) atomicAdd(&histB[i], c);
  }
  __threadfence();
  if (tid == 0) lastS = (atomicAdd(&p[P_DONEB], 1) == (int)gridDim.x - 1);
  __syncthreads();
  if (!lastS) return;
  __threadfence();
  // ---- exact threshold (last block) ----
  uint32_t uLo = (uint32_t)p[P_ULO];
  if (tid < 2) vres[tid] = __uint_as_float(uLo);
  for (int tgt = 0; tgt < 2; ++tgt) {
    __syncthreads();
    const int* hh = histB + tgt * 2048;
    int rank = (tgt == 0) ? p[P_RA1] : p[P_RA2];
    int binA = (tgt == 0) ? binA1 : binA2;
    int base = tid * 8;
    int cc[8]; int s = 0;
#pragma unroll
    for (int w = 0; w < 8; ++w) { cc[w] = hh[base + w]; s += cc[w]; }
    part[tid] = s;
    __syncthreads();
    if (tid == 0) { int a = 0; for (int i = 0; i < 256; ++i) { excl[i] = a; a += part[i]; } }
    __syncthreads();
    int pre = excl[tid];
    if (pre <= rank && rank < pre + s) {
      int a = pre;
      for (int w = 0; w < 8; ++w) {
        if (rank < a + cc[w]) {
          uint32_t bits = uLo + ((uint32_t)binA << 11) + (uint32_t)(base + w);
          vres[tgt] = __uint_as_float(bits);
          break;
        }
        a += cc[w];
      }
    }
  }
  __syncthreads();
  if (tid == 0) {
    float med = 0.5f * (vres[0] + vres[1]);     // np.median: mean of two mid order stats
    float thr = (5.0f * med) / 0.6745f;         // reference float32 expression order
    p[P_THR] = __float_as_int(thr);
    sthr = thr;
    out[2 * OUT_K] = thr;
  }
  if (tid < 4) cnt[tid] = 0;
  __syncthreads();
  // ---- finalize (same block) ----
  float thr = sthr;
  int nC = p[P_CANDN]; if (nC > CAND_CAP) nC = CAND_CAP;
  const int* cnd;                              // sorted candidate array to use
  if (nC <= CSORT_CAP) {
    // parallel rank sort entirely in LDS (indices are distinct)
    for (int i = tid; i < nC; i += 256) cl[i] = cand[i];
    __syncthreads();
    int myv[CSORT_CAP / 256], myr[CSORT_CAP / 256], nh = 0;
    for (int i = tid; i < nC; i += 256) {
      int v = cl[i];
      int r = 0;
      for (int q = 0; q < nC; ++q) r += (cl[q] < v) ? 1 : 0;
      myv[nh] = v; myr[nh] = r; ++nh;
    }
    __syncthreads();
    for (int t = 0; t < nh; ++t) cl[myr[t]] = myv[t];
    __syncthreads();
    cnd = cl;
  } else {                                      // escape hatch, never expected
    if (tid == 0) isort(cand, nC);
    __syncthreads();
    cnd = cand;
  }
  // pair (p,p+1) processed exactly once: from candidate p (right pair),
  // or from candidate p+1 iff p not a candidate.
  for (int k = tid; k < nC; k += 256) {
    int c = cnd[k];
    bool prevAdj = (k > 0) && (cnd[k - 1] == c - 1);
    if (c > 0 && !prevAdj) eval_pair(x, c - 1, thr, pe, px, ne, nx, cnt);
    if (c <= N - 2) eval_pair(x, c, thr, pe, px, ne, nx, cnt);
  }
  __syncthreads();
  int nPE = min(cnt[0], PAIR_CAP), nPX = min(cnt[1], PAIR_CAP);
  int nNE = min(cnt[2], PAIR_CAP), nNX = min(cnt[3], PAIR_CAP);
  if (tid == 0) { isort(pe, nPE); isort(px, nPX); }
  else if (tid == 1) { isort(ne, nNE); isort(nx, nNX); }
  __syncthreads();
  if (tid < 64) {                               // wave 0 only; no barriers inside
    int t0 = proc_pol(x, N, +1, pe, nPE, px, nPX, pkP, tid);
    int t1 = proc_pol(x, N, -1, ne, nNE, nx, nNX, pkN, tid);
    if (tid == 0) { nPk[0] = t0; nPk[1] = t1; }
  }
  __syncthreads();
  for (int j = tid; j < nPk[0]; j += 256) out[j] = (float)pkP[j];
  for (int j = tid; j < nPk[1]; j += 256) out[OUT_K + j] = (float)pkN[j];
}

extern "C" void kernel_launch(void* const* d_in, const int* in_sizes, int n_in,
                              void* d_out, int out_size, void* d_ws, size_t ws_size,
                              hipStream_t stream) {
  const float* x = (const float*)d_in[0];
  int N = in_sizes[0];
  float* out = (float*)d_out;
  char* ws = (char*)d_ws;

  int* shist  = (int*)(ws + WS_SHIST);
  int* histA  = (int*)(ws + WS_HISTA);
  int* histB  = (int*)(ws + WS_HISTB);
  int* params = (int*)(ws + WS_PARAMS);
  int* cand   = (int*)(ws + WS_CAND);
  int* list   = (int*)(ws + WS_LIST);

  int OUT_K = (out_size - 1) / 2;  // 65536
  int nInts = WS_ZERO_BYTES / 4;
  int prepN = 2 * OUT_K;           // covers both zero region and pad region

  k_prep<<<(prepN + 255) / 256, 256, 0, stream>>>((int*)ws, nInts, out, prepN);
  k_sample<<<64, 256, 0, stream>>>(x, N, shist, params);
  k_main<<<MAIN_BLOCKS, 256, 0, stream>>>(x, N, params, list, cand);
  k_stageA<<<AB_BLOCKS, 256, 0, stream>>>(list, params, histA, N);
  k_stageB<<<AB_BLOCKS, 256, 0, stream>>>(x, N, list, params, histB, cand, out, OUT_K);
}